// Round 2
// baseline (3258.880 us; speedup 1.0000x reference)
//
#include <hip/hip_runtime.h>

// ---------------------------------------------------------------------------
// Bidirectional 2-layer GRU (B=256, T=256, H=256, IN0=4) + head.  v2.
//
// Round-1 lesson: streaming full Whh from L2 every step is per-CU-L2-port
// bound (393 KB/step/CU -> ~6k cyc/step floor). v2 inverts the split:
//   - each WG owns (64 batch rows x 64 hidden cols) of one direction
//   - MFMA computes D[gate][batch] = Whh_slice * h^T, so the CONSTANT weight
//     slice lives in VGPRs (A-operand, ~100 regs/wave, loaded once)
//   - per step only the 32 KB h panel moves (global slabs, frag-packed,
//     global_load_lds), exchanged between the 4 col-group WGs of a row group
//     via agent-scope release/acquire fences + u16 step flags
//   - L0: K=4 input proj + biases folded in as a 9th MFMA K-slice ([x | 1.0])
//   - L1: bih+bhh(r,z) folded into xp1 GEMM epilogue; bhh_n kept separate
//
// Kernels: prep_wf (pack Whh+ext -> bf16 frags), prep_w1b, gru_step<0> (32
// WGs), bwd255, xp1_gemm (-> gathered [cg][t][b][192] bf16), gru_step<1>
// (16 WGs), head.
//
// Workspace (bytes):
//   0          wfall : 3*48*9*64*16       = 1,327,104
//   1327104    w1b   : 768*512*2          =   786,432
//   2113536    h0c   : 65536*512*2        = 67,108,864
//   69222400   xp1g  : 4*256*256*192*2    = 100,663,296
//   169885696  hb255 : 256*256*4          =   262,144
//   170147840  hfl   : 256*256*4          =   262,144
//   170409984  hg0   : 2*2*4*4*8192      =   524,288
//   170934272  hg1   : 2*4*4*8192        =   262,144
//   171196416  flags : 512
// ---------------------------------------------------------------------------

typedef __attribute__((ext_vector_type(8))) short short8;
typedef __attribute__((ext_vector_type(4))) float f32x4;

__device__ __forceinline__ short f2bf(float f) {
  union { float f; unsigned u; } v; v.f = f;
  unsigned r = v.u + 0x7fffu + ((v.u >> 16) & 1u);
  return (short)(r >> 16);
}
__device__ __forceinline__ float bf2f(unsigned short b) {
  union { unsigned u; float f; } v; v.u = ((unsigned)b) << 16; return v.f;
}
__device__ __forceinline__ float sigf(float x) {
  return __builtin_amdgcn_rcpf(1.f + __expf(-x));
}
__device__ __forceinline__ float tanhf_(float x) {
  return 1.f - 2.f * __builtin_amdgcn_rcpf(1.f + __expf(2.f * x));
}
__device__ __forceinline__ void gload_lds16(const void* g, void* s) {
  __builtin_amdgcn_global_load_lds(
      (const __attribute__((address_space(1))) unsigned int*)g,
      (__attribute__((address_space(3))) unsigned int*)s, 16, 0, 0);
}

// --------------------------- prep kernels ----------------------------------
// wfall[mat][nt48][kk9][lane][8]:
//  kk<8 : W[mat](row = nt*16+l15, k = kk*32+lhi*8+s), mats {Whh0d0,Whh0d1,Whh1d0}
//  kk=8 : ext cols c = lhi*8+s: c<4 -> Wih0 (r/z rows, L0 mats only);
//         c==4 -> bias col (L0: bih+bhh for r/z, bhh for n; L1: unused=0)
__global__ __launch_bounds__(256) void prep_wf(
    const float* __restrict__ whh0, const float* __restrict__ whh1,
    const float* __restrict__ wih0, const float* __restrict__ bih0,
    const float* __restrict__ bhh0, short* __restrict__ out) {
  int tid = blockIdx.x * 256 + threadIdx.x;     // 0..82943
  int l = tid & 63;
  int rest = tid >> 6;                          // 0..1295
  int kk = rest % 9;
  int nt = (rest / 9) % 48;
  int m  = rest / (9 * 48);
  int l15 = l & 15, lhi = l >> 4;
  int row = nt * 16 + l15;                      // gate row 0..767
  int kind = nt >> 4;                           // 0=r 1=z 2=n
  short8 o = {};
  if (kk < 8) {
    const float* src = (m < 2) ? (whh0 + (size_t)m * 768 * 256) : whh1;
    const float* p = src + (size_t)row * 256 + kk * 32 + lhi * 8;
    #pragma unroll
    for (int s = 0; s < 8; ++s) o[s] = f2bf(p[s]);
  } else if (m < 2) {
    #pragma unroll
    for (int s = 0; s < 8; ++s) {
      int c = lhi * 8 + s;
      float v = 0.f;
      if (c < 4) { if (kind < 2) v = wih0[((size_t)m * 768 + row) * 4 + c]; }
      else if (c == 4) {
        v = bhh0[m * 768 + row];
        if (kind < 2) v += bih0[m * 768 + row];
      }
      o[s] = f2bf(v);
    }
  }
  ((short8*)out)[tid] = o;
}

__global__ __launch_bounds__(256) void prep_w1b(const float* __restrict__ wih1,
                                                short* __restrict__ out) {
  int i = blockIdx.x * 256 + threadIdx.x;
  const float* p = wih1 + (size_t)i * 8;
  short8 o;
  #pragma unroll
  for (int s = 0; s < 8; ++s) o[s] = f2bf(p[s]);
  ((short8*)out)[i] = o;
}

// --------------------------- recurrence ------------------------------------
// 8 waves (wm=w>>1 : hidden-col subtile, wn=w&1 : batch half).
// A (weights) persistent in VGPRs. B (h panel) via frag-packed global slabs.
template <int LAYER>
__global__ __launch_bounds__(512, 2) void gru_step(
    const float* __restrict__ x,        // L0 [256][256][4]
    const float* __restrict__ wih0,     // L0 [2][768][4]
    const float* __restrict__ bih0,     // L0 [2][768]
    const float* __restrict__ bhh1,     // L1 [2][768]
    const short* __restrict__ wf,       // [3][48][9][64][8]
    const unsigned short* __restrict__ xp1g, // L1 [4][256][256][192]
    short* __restrict__ h0c,            // L0 out [b][t][512]
    float* __restrict__ hfl,            // L1 out [b][256]
    short* __restrict__ hglob,          // slab buffers (this layer)
    unsigned short* __restrict__ flags16) {
  constexpr int NDIR = (LAYER == 0) ? 2 : 1;
  constexpr int KK   = (LAYER == 0) ? 9 : 8;
  const int wg  = blockIdx.x;
  const int dir = (LAYER == 0) ? (wg >> 4) : 0;
  const int bg  = (LAYER == 0) ? ((wg >> 2) & 3) : (wg >> 2);
  const int cg  = wg & 3;
  const int b0  = bg * 64;
  const int tid = threadIdx.x;
  const int w = tid >> 6, l = tid & 63, l15 = l & 15, lhi = l >> 4;
  const int wm = w >> 1, wn = w & 1;
  const int grp = (LAYER == 0) ? (dir * 4 + bg) : bg;

  __shared__ __align__(16) short Bext[18432];   // 32KB B panel + 4KB ext
  __shared__ __align__(16) short bounce[4096];  // 8KB h redistribution

  const unsigned long long* f64 = (const unsigned long long*)flags16;

  // persistent A fragments (weights)
  short8 a[3][9];
  {
    const int mat = (LAYER == 0) ? dir : 2;
    #pragma unroll
    for (int g = 0; g < 3; ++g) {
      const int ntA = g * 16 + cg * 4 + wm;
      #pragma unroll
      for (int kk = 0; kk < KK; ++kk)
        a[g][kk] = ((const short8*)wf)[((size_t)(mat * 48 + ntA) * 9 + kk) * 64 + l];
    }
  }

  float4 wn4[4]; float bihn[4]; float bhhn[4];
  #pragma unroll
  for (int i = 0; i < 4; ++i) {
    const int crel = wm * 16 + lhi * 4 + i;
    if (LAYER == 0) {
      const int grow = 512 + cg * 64 + crel;
      wn4[i]  = ((const float4*)wih0)[dir * 768 + grow];
      bihn[i] = bih0[dir * 768 + grow];
      bhhn[i] = 0.f;
    } else {
      wn4[i] = float4{0, 0, 0, 0}; bihn[i] = 0.f;
      bhhn[i] = bhh1[512 + cg * 64 + crel];
    }
  }

  float hreg[2][4] = {{0, 0, 0, 0}, {0, 0, 0, 0}};

  for (int t = 0; t < 256; ++t) {
    const int tact = (LAYER == 0 && dir == 1) ? (255 - t) : t;

    // ---- early independent loads (before sync; static data) ----
    float4 xv[2]; ushort4 xq[2][3];
    if (LAYER == 0) {
      #pragma unroll
      for (int nt = 0; nt < 2; ++nt)
        xv[nt] = ((const float4*)x)[(size_t)(b0 + wn * 32 + nt * 16 + l15) * 256 + tact];
    } else {
      #pragma unroll
      for (int nt = 0; nt < 2; ++nt) {
        const size_t rb = ((size_t)(cg * 256 + t) * 256 + (b0 + wn * 32 + nt * 16 + l15)) * 192;
        #pragma unroll
        for (int g = 0; g < 3; ++g)
          xq[nt][g] = *(const ushort4*)(xp1g + rb + g * 64 + wm * 16 + lhi * 4);
      }
    }
    short8 extv = {};
    if (LAYER == 0 && tid < 256) {
      if (lhi == 0) {                       // line (ntg=w, l): only c<8 lanes
        const int bb = b0 + w * 16 + l15;
        float4 xe = ((const float4*)x)[(size_t)bb * 256 + tact];
        extv[0] = f2bf(xe.x); extv[1] = f2bf(xe.y);
        extv[2] = f2bf(xe.z); extv[3] = f2bf(xe.w);
        extv[4] = (short)0x3F80;            // 1.0 bias column
      }
    }

    // ---- wait for peers' h_t slabs ----
    for (;;) {
      unsigned long long v = __hip_atomic_load(&f64[grp], __ATOMIC_RELAXED,
                                               __HIP_MEMORY_SCOPE_AGENT);
      if ((int)(v & 0xFFFF) >= t && (int)((v >> 16) & 0xFFFF) >= t &&
          (int)((v >> 32) & 0xFFFF) >= t && (int)((v >> 48) & 0xFFFF) >= t)
        break;
      __builtin_amdgcn_s_sleep(2);
    }
    __builtin_amdgcn_fence(__ATOMIC_ACQUIRE, "agent");

    // ---- stage h panel (4 slabs, frag-packed, linear) ----
    const int ph = t & 1;
    {
      const int rdbase = ((ph * NDIR + dir) * 4 + bg) * 4;
      #pragma unroll
      for (int g4 = 0; g4 < 4; ++g4)
        gload_lds16(hglob + (size_t)(rdbase + g4) * 4096 + tid * 8,
                    &Bext[g4 * 4096 + tid * 8]);
    }
    if (LAYER == 0 && tid < 256) *(short8*)&Bext[16384 + tid * 8] = extv;
    __syncthreads();

    // ---- gates GEMM + elementwise ----
    f32x4 acc[3][2] = {};
    #pragma unroll
    for (int nt = 0; nt < 2; ++nt) {
      const int ntg = wn * 2 + nt;
      #pragma unroll
      for (int kk = 0; kk < KK; ++kk) {
        short8 bf;
        if (kk < 8) bf = *(const short8*)&Bext[(kk * 4 + ntg) * 512 + l * 8];
        else        bf = *(const short8*)&Bext[16384 + (ntg * 64 + l) * 8];
        acc[0][nt] = __builtin_amdgcn_mfma_f32_16x16x32_bf16(a[0][kk], bf, acc[0][nt], 0, 0, 0);
        acc[1][nt] = __builtin_amdgcn_mfma_f32_16x16x32_bf16(a[1][kk], bf, acc[1][nt], 0, 0, 0);
        acc[2][nt] = __builtin_amdgcn_mfma_f32_16x16x32_bf16(a[2][kk], bf, acc[2][nt], 0, 0, 0);
      }
      float xr4[4], xz4[4], xn4[4];
      if (LAYER == 1) {
        xr4[0] = bf2f(xq[nt][0].x); xr4[1] = bf2f(xq[nt][0].y);
        xr4[2] = bf2f(xq[nt][0].z); xr4[3] = bf2f(xq[nt][0].w);
        xz4[0] = bf2f(xq[nt][1].x); xz4[1] = bf2f(xq[nt][1].y);
        xz4[2] = bf2f(xq[nt][1].z); xz4[3] = bf2f(xq[nt][1].w);
        xn4[0] = bf2f(xq[nt][2].x); xn4[1] = bf2f(xq[nt][2].y);
        xn4[2] = bf2f(xq[nt][2].z); xn4[3] = bf2f(xq[nt][2].w);
      } else {
        #pragma unroll
        for (int i = 0; i < 4; ++i) { xr4[i] = 0; xz4[i] = 0; xn4[i] = 0; }
      }
      const int brow = wn * 32 + nt * 16 + l15;
      #pragma unroll
      for (int i = 0; i < 4; ++i) {
        const float racc = acc[0][nt][i], zacc = acc[1][nt][i], nacc = acc[2][nt][i];
        float r, z, n;
        if (LAYER == 0) {
          r = sigf(racc); z = sigf(zacc);   // biases + Wih*x folded via ext col
          const float xn = xv[nt].x * wn4[i].x + xv[nt].y * wn4[i].y +
                           xv[nt].z * wn4[i].z + xv[nt].w * wn4[i].w + bihn[i];
          n = tanhf_(xn + r * nacc);        // nacc = Whh_n h + bhh_n
        } else {
          r = sigf(racc + xr4[i]);          // xp has bih+bhh folded (r,z)
          z = sigf(zacc + xz4[i]);
          n = tanhf_(xn4[i] + r * (nacc + bhhn[i]));
        }
        const float h = n + z * (hreg[nt][i] - n);
        hreg[nt][i] = h;
        const int ccol = wm * 16 + lhi * 4 + i;
        bounce[brow * 64 + (((ccol >> 3) ^ (brow & 7)) << 3) + (ccol & 7)] = f2bf(h);
      }
    }
    __syncthreads();

    // ---- redistribute: bounce -> frag-packed slab (+ h0c for L0) ----
    {
      const int kkl = tid >> 8, ntl = (tid >> 6) & 3, ll = tid & 63;
      const int br = ntl * 16 + (ll & 15);
      const int c0 = kkl * 32 + (ll >> 4) * 8;
      const short8 v = *(const short8*)&bounce[br * 64 + (((c0 >> 3) ^ (br & 7)) << 3)];
      const int wrbase = (((ph ^ 1) * NDIR + dir) * 4 + bg) * 4 + cg;
      *(short8*)(hglob + (size_t)wrbase * 4096 + tid * 8) = v;
      if (LAYER == 0)
        __builtin_nontemporal_store(v,
            (short8*)(h0c + ((size_t)(b0 + br) * 256 + tact) * 512 + dir * 256 + cg * 64 + c0));
    }
    __syncthreads();
    if (tid == 0) {
      __builtin_amdgcn_fence(__ATOMIC_RELEASE, "agent");
      __hip_atomic_store(&flags16[grp * 4 + cg], (unsigned short)(t + 1),
                         __ATOMIC_RELAXED, __HIP_MEMORY_SCOPE_AGENT);
    }
  }

  if (LAYER == 1) {
    #pragma unroll
    for (int nt = 0; nt < 2; ++nt)
      #pragma unroll
      for (int i = 0; i < 4; ++i)
        hfl[(size_t)(b0 + wn * 32 + nt * 16 + l15) * 256 + cg * 64 + wm * 16 + lhi * 4 + i] =
            hreg[nt][i];
  }
}

// --------------------------- xp1 GEMM --------------------------------------
// [65536,512]@[512,768]^T bf16; epilogue adds bih1 (+bhh1 for r/z) and stores
// gathered layout xp1g[cg][t][b][idx192] (idx = kind*64 + (c&63)).
__global__ __launch_bounds__(256, 2) void xp1_gemm(
    const short* __restrict__ h0c, const short* __restrict__ w1b,
    const float* __restrict__ bih1, const float* __restrict__ bhh1,
    unsigned short* __restrict__ xp1g) {
  const int mb = blockIdx.x, nb = blockIdx.y;
  const int tid = threadIdx.x;
  const int w = tid >> 6, l = tid & 63, l15 = l & 15, lhi = l >> 4;
  const int wm = w >> 1, wn = w & 1;
  __shared__ __align__(16) short As[128 * 64];
  __shared__ __align__(16) short Bs[128 * 64];
  f32x4 acc[4][4] = {};

  for (int ks = 0; ks < 8; ++ks) {
    short8 sa[4], sb[4];
    #pragma unroll
    for (int c = 0; c < 4; ++c) {
      int li = w * 256 + c * 64 + l;
      int row = li >> 3, cgr = li & 7;
      sa[c] = *(const short8*)(h0c + (size_t)(mb * 128 + row) * 512 + ks * 64 + cgr * 8);
      sb[c] = *(const short8*)(w1b + (size_t)(nb * 128 + row) * 512 + ks * 64 + cgr * 8);
    }
    __syncthreads();
    #pragma unroll
    for (int c = 0; c < 4; ++c) {
      int li = w * 256 + c * 64 + l;
      int row = li >> 3, cgr = li & 7;
      int sl = ((cgr ^ (row & 7)) << 3);
      *(short8*)&As[row * 64 + sl] = sa[c];
      *(short8*)&Bs[row * 64 + sl] = sb[c];
    }
    __syncthreads();
    short8 af[4][2], bfr[4][2];
    #pragma unroll
    for (int mt = 0; mt < 4; ++mt)
      #pragma unroll
      for (int kk = 0; kk < 2; ++kk) {
        int row = wm * 64 + mt * 16 + l15;
        int g = kk * 4 + lhi;
        af[mt][kk] = *(const short8*)&As[row * 64 + ((g ^ (row & 7)) << 3)];
      }
    #pragma unroll
    for (int nt2 = 0; nt2 < 4; ++nt2)
      #pragma unroll
      for (int kk = 0; kk < 2; ++kk) {
        int row = wn * 64 + nt2 * 16 + l15;
        int g = kk * 4 + lhi;
        bfr[nt2][kk] = *(const short8*)&Bs[row * 64 + ((g ^ (row & 7)) << 3)];
      }
    #pragma unroll
    for (int kk = 0; kk < 2; ++kk)
      #pragma unroll
      for (int mt = 0; mt < 4; ++mt)
        #pragma unroll
        for (int nt2 = 0; nt2 < 4; ++nt2)
          acc[mt][nt2] = __builtin_amdgcn_mfma_f32_16x16x32_bf16(
              af[mt][kk], bfr[nt2][kk], acc[mt][nt2], 0, 0, 0);
  }

  #pragma unroll
  for (int nt2 = 0; nt2 < 4; ++nt2) {
    const int gate = nb * 128 + wn * 64 + nt2 * 16 + l15;
    const int kind = gate >> 8, c = gate & 255;
    const int cgx = c >> 6, idx = kind * 64 + (c & 63);
    const float bias = bih1[gate] + ((kind < 2) ? bhh1[gate] : 0.f);
    #pragma unroll
    for (int mt = 0; mt < 4; ++mt)
      #pragma unroll
      for (int i = 0; i < 4; ++i) {
        const int rt = mb * 128 + wm * 64 + mt * 16 + lhi * 4 + i;
        const int b = rt >> 8, tt = rt & 255;
        xp1g[((size_t)(cgx * 256 + tt) * 256 + b) * 192 + idx] =
            (unsigned short)f2bf(acc[mt][nt2][i] + bias);
      }
  }
}

// --------------------------- layer-1 bwd single step -----------------------
__global__ __launch_bounds__(256) void bwd255(
    const short* __restrict__ h0c, const float* __restrict__ wih1,
    const float* __restrict__ bih1, const float* __restrict__ bhh1,
    float* __restrict__ hb) {
  const int b = blockIdx.x, j = threadIdx.x;
  __shared__ __align__(16) float hrow[512];
  const unsigned short* hr = (const unsigned short*)(h0c + (size_t)(b * 256 + 255) * 512);
  for (int k = j; k < 512; k += 256) hrow[k] = bf2f(hr[k]);
  __syncthreads();
  const float4* hr4 = (const float4*)hrow;
  float g[3];
  #pragma unroll
  for (int gi = 0; gi < 3; ++gi) {
    const float4* wr = (const float4*)(wih1 + (size_t)768 * 512 + (size_t)(gi * 256 + j) * 512);
    float s = 0.f;
    #pragma unroll 4
    for (int k = 0; k < 128; ++k) {
      float4 aq = hr4[k], bq = wr[k];
      s += aq.x * bq.x + aq.y * bq.y + aq.z * bq.z + aq.w * bq.w;
    }
    g[gi] = s + bih1[768 + gi * 256 + j];
  }
  float r = sigf(g[0] + bhh1[768 + j]);
  float z = sigf(g[1] + bhh1[768 + 256 + j]);
  float n = tanhf_(g[2] + r * bhh1[768 + 512 + j]);
  hb[b * 256 + j] = (1.f - z) * n;
}

// --------------------------- head ------------------------------------------
__global__ __launch_bounds__(64) void head(
    const float* __restrict__ hf, const float* __restrict__ hb,
    const float* __restrict__ wout, const float* __restrict__ bout,
    float* __restrict__ out) {
  const int b = blockIdx.x, l = threadIdx.x;
  float s0 = 0.f, s1 = 0.f, s2 = 0.f;
  for (int k = l; k < 256; k += 64) {
    float v = hf[b * 256 + k] + hb[b * 256 + k];
    s0 += v * wout[k];
    s1 += v * wout[256 + k];
    s2 += v * wout[512 + k];
  }
  #pragma unroll
  for (int off = 32; off > 0; off >>= 1) {
    s0 += __shfl_down(s0, off);
    s1 += __shfl_down(s1, off);
    s2 += __shfl_down(s2, off);
  }
  if (l == 0) {
    s0 += bout[0]; s1 += bout[1]; s2 += bout[2];
    float m = fmaxf(s0, fmaxf(s1, s2));
    float e0 = __expf(s0 - m), e1 = __expf(s1 - m), e2 = __expf(s2 - m);
    float inv = 1.f / (e0 + e1 + e2);
    out[b * 3 + 0] = e0 * inv;
    out[b * 3 + 1] = e1 * inv;
    out[b * 3 + 2] = e2 * inv;
  }
}

// --------------------------- launch ----------------------------------------
extern "C" void kernel_launch(void* const* d_in, const int* in_sizes, int n_in,
                              void* d_out, int out_size, void* d_ws, size_t ws_size,
                              hipStream_t stream) {
  const float* x    = (const float*)d_in[0];
  const float* wih0 = (const float*)d_in[1];
  const float* whh0 = (const float*)d_in[2];
  const float* bih0 = (const float*)d_in[3];
  const float* bhh0 = (const float*)d_in[4];
  const float* wih1 = (const float*)d_in[5];
  const float* whh1 = (const float*)d_in[6];
  const float* bih1 = (const float*)d_in[7];
  const float* bhh1 = (const float*)d_in[8];
  const float* wout = (const float*)d_in[9];
  const float* bout = (const float*)d_in[10];
  float* out = (float*)d_out;

  char* ws = (char*)d_ws;
  short* wfall          = (short*)(ws + 0);
  short* w1b            = (short*)(ws + 1327104);
  short* h0c            = (short*)(ws + 2113536);
  unsigned short* xp1g  = (unsigned short*)(ws + 69222400);
  float* hb255          = (float*)(ws + 169885696);
  float* hfl            = (float*)(ws + 170147840);
  short* hg0            = (short*)(ws + 170409984);
  short* hg1            = (short*)(ws + 170934272);
  unsigned short* flg   = (unsigned short*)(ws + 171196416);

  // zero slab buffers (h_0 = 0) + step flags
  hipMemsetAsync(ws + 170409984, 0, 524288 + 262144 + 512, stream);

  prep_wf<<<324, 256, 0, stream>>>(whh0, whh1, wih0, bih0, bhh0, wfall);
  prep_w1b<<<192, 256, 0, stream>>>(wih1, w1b);
  gru_step<0><<<32, 512, 0, stream>>>(x, wih0, bih0, nullptr, wfall, nullptr,
                                      h0c, nullptr, hg0, flg);
  bwd255<<<256, 256, 0, stream>>>(h0c, wih1, bih1, bhh1, hb255);
  xp1_gemm<<<dim3(512, 6), 256, 0, stream>>>(h0c, w1b, bih1, bhh1, xp1g);
  gru_step<1><<<16, 512, 0, stream>>>(nullptr, nullptr, nullptr, bhh1, wfall,
                                      xp1g, nullptr, hfl, hg1, flg + 32);
  head<<<256, 64, 0, stream>>>(hfl, hb255, wout, bout, out);
}

// Round 3
// 2413.538 us; speedup vs baseline: 1.3503x; 1.3503x over previous
//
#include <hip/hip_runtime.h>

// ---------------------------------------------------------------------------
// Bidirectional 2-layer GRU (B=256, T=256, H=256, IN0=4) + head.  v3.
//
// v1 lesson: streaming Whh from L2 per step = per-CU L2-port bound.
// v2 lesson: cross-WG h exchange via global memory = XCD-coherence disaster.
// v3: each WG = 16 batch rows x FULL hidden state of one direction.
//     - whole Whh lives in VGPRs/AGPRs: 8 waves x 6 N-tiles x 9 K-slices
//       (9th slice = ext column carrying Wih0 (r/z), biases; B-ext = [x|1]).
//     - per step: h panel (16x256 bf16 = 8 KB) double-buffered in swizzled
//       LDS; ONE __syncthreads per step; zero inter-WG communication.
//     - L0: 32 WGs (16/dir); L1: 16 WGs; xp1 GEMM between layers.
//
// Workspace (bytes):
//   0          wfall : 3*48*9*64*16 = 1,327,104
//   1327104    w1b   : 768*512*2    =   786,432
//   2113536    h0c   : 65536*512*2  = 67,108,864   rows = b*256+t, 512 cols
//   69222400   xp1g  : [t][b][768]*2= 100,663,296
//   169885696  hb255 : 256*256*4    =   262,144
//   170147840  hfl   : 256*256*4    =   262,144
// ---------------------------------------------------------------------------

typedef __attribute__((ext_vector_type(8))) short short8;
typedef __attribute__((ext_vector_type(4))) short sh4;
typedef __attribute__((ext_vector_type(4))) float f32x4;

__device__ __forceinline__ short f2bf(float f) {
  union { float f; unsigned u; } v; v.f = f;
  unsigned r = v.u + 0x7fffu + ((v.u >> 16) & 1u);
  return (short)(r >> 16);
}
__device__ __forceinline__ float bf2f(unsigned short b) {
  union { unsigned u; float f; } v; v.u = ((unsigned)b) << 16; return v.f;
}
__device__ __forceinline__ float sigf(float x) {
  return __builtin_amdgcn_rcpf(1.f + __expf(-x));
}
__device__ __forceinline__ float tanhf_(float x) {
  return 1.f - 2.f * __builtin_amdgcn_rcpf(1.f + __expf(2.f * x));
}
#define US4_GET(v, i) ((i) == 0 ? (v).x : (i) == 1 ? (v).y : (i) == 2 ? (v).z : (v).w)

// --------------------------- prep kernels ----------------------------------
// wfall[mat][nt48][kk9][lane][8]:
//  kk<8 : W[mat](row = nt*16+l15, k = kk*32+lhi*8+s); mats {Whh0d0,Whh0d1,Whh1d0}
//  kk=8 : ext cols c=lhi*8+s:
//    m<2 : c<4 -> Wih0 (r/z rows only); c==4 -> bias (r/z: bih+bhh, n: bhh)
//    m==2: c==4 && n-row -> bhh1; else 0  (r/z biases folded in xp1 GEMM)
__global__ __launch_bounds__(256) void prep_wf(
    const float* __restrict__ whh0, const float* __restrict__ whh1,
    const float* __restrict__ wih0, const float* __restrict__ bih0,
    const float* __restrict__ bhh0, const float* __restrict__ bhh1,
    short* __restrict__ out) {
  int tid = blockIdx.x * 256 + threadIdx.x;     // 0..82943
  int l = tid & 63;
  int rest = tid >> 6;
  int kk = rest % 9;
  int nt = (rest / 9) % 48;
  int m  = rest / (9 * 48);
  int l15 = l & 15, lhi = l >> 4;
  int row = nt * 16 + l15;                      // gate row 0..767
  int kind = nt >> 4;                           // 0=r 1=z 2=n
  short8 o = {};
  if (kk < 8) {
    const float* src = (m < 2) ? (whh0 + (size_t)m * 768 * 256) : whh1;
    const float* p = src + (size_t)row * 256 + kk * 32 + lhi * 8;
    #pragma unroll
    for (int s = 0; s < 8; ++s) o[s] = f2bf(p[s]);
  } else {
    #pragma unroll
    for (int s = 0; s < 8; ++s) {
      int c = lhi * 8 + s;
      float v = 0.f;
      if (m < 2) {
        if (c < 4) { if (kind < 2) v = wih0[((size_t)m * 768 + row) * 4 + c]; }
        else if (c == 4) {
          v = bhh0[m * 768 + row];
          if (kind < 2) v += bih0[m * 768 + row];
        }
      } else {
        if (c == 4 && kind == 2) v = bhh1[row];
      }
      o[s] = f2bf(v);
    }
  }
  ((short8*)out)[tid] = o;
}

__global__ __launch_bounds__(256) void prep_w1b(const float* __restrict__ wih1,
                                                short* __restrict__ out) {
  int i = blockIdx.x * 256 + threadIdx.x;
  const float* p = wih1 + (size_t)i * 8;
  short8 o;
  #pragma unroll
  for (int s = 0; s < 8; ++s) o[s] = f2bf(p[s]);
  ((short8*)out)[i] = o;
}

// --------------------------- recurrence ------------------------------------
// WG = 512 threads (8 waves). Wave w owns hidden cols [32w, 32w+32):
// tiles g*16 + 2w + {0,1} for g = r,z,n. D[gate][batch]: lane holds
// (gate rows lhi*4+i, batch col l15). h panel in LDS [16][256] bf16,
// 16B-granule XOR swizzle g' = g ^ (row&7), double buffered.
template <int LAYER>
__global__ __launch_bounds__(512, 1) void gru_step(
    const float* __restrict__ x,        // L0 [256][256][4]
    const float* __restrict__ wih0,     // L0 [2][768][4]
    const float* __restrict__ bih0,     // L0 [2][768]
    const short* __restrict__ wf,       // [3][48][9][64][8]
    const unsigned short* __restrict__ xp1g, // L1 [t][b][768]
    short* __restrict__ h0c,            // L0 out: rows b*256+t, 512 cols
    float* __restrict__ hfl) {          // L1 out [b][256]
  const int wg  = blockIdx.x;
  const int dir = (LAYER == 0) ? (wg >> 4) : 0;
  const int bt  = (LAYER == 0) ? (wg & 15) : wg;
  const int b0  = bt * 16;
  const int tid = threadIdx.x;
  const int w = tid >> 6, l = tid & 63, l15 = l & 15, lhi = l >> 4;

  __shared__ __align__(16) short hb[2][4096];      // [buf][16 rows][256 cols]
  __shared__ __align__(16) short ext2[2][640];     // [buf][16 rows][40]

  for (int i = tid; i < 4096; i += 512) hb[0][i] = 0;
  for (int i = tid; i < 1280; i += 512) ((short*)ext2)[i] = 0;
  __syncthreads();
  if (LAYER == 0) {
    if (tid < 16) {
      const int t0 = dir ? 255 : 0;
      float4 xe = ((const float4*)x)[(size_t)(b0 + tid) * 256 + t0];
      short8 e = {};
      e[0] = f2bf(xe.x); e[1] = f2bf(xe.y); e[2] = f2bf(xe.z); e[3] = f2bf(xe.w);
      e[4] = (short)0x3F80;
      *(short8*)&ext2[0][tid * 40] = e;
    }
  } else {
    if (tid < 16) {
      short8 e = {};
      e[4] = (short)0x3F80;
      *(short8*)&ext2[0][tid * 40] = e;
    }
  }

  // ---- persistent weight fragments ----
  const int mat = (LAYER == 0) ? dir : 2;
  short8 a[3][2][9];
  #pragma unroll
  for (int g = 0; g < 3; ++g)
    #pragma unroll
    for (int s = 0; s < 2; ++s) {
      const int tile = g * 16 + 2 * w + s;
      #pragma unroll
      for (int kk = 0; kk < 9; ++kk)
        a[g][s][kk] = ((const short8*)wf)[((size_t)(mat * 48 + tile) * 9 + kk) * 64 + l];
    }

  float4 wn4[2][4]; float bihn[2][4];
  if (LAYER == 0) {
    #pragma unroll
    for (int s = 0; s < 2; ++s)
      #pragma unroll
      for (int i = 0; i < 4; ++i) {
        const int hcol = 32 * w + 16 * s + lhi * 4 + i;
        wn4[s][i]  = ((const float4*)wih0)[dir * 768 + 512 + hcol];
        bihn[s][i] = bih0[dir * 768 + 512 + hcol];
      }
  }

  float hreg[2][4] = {{0, 0, 0, 0}, {0, 0, 0, 0}};
  __syncthreads();

  for (int t = 0; t < 256; ++t) {
    const int cur = t & 1;

    // ---- prefetch x_{t+1} -> ext[cur^1] (L0) ----
    if (LAYER == 0 && tid < 16 && t < 255) {
      const int tn = dir ? 254 - t : t + 1;
      float4 xe = ((const float4*)x)[(size_t)(b0 + tid) * 256 + tn];
      short8 e = {};
      e[0] = f2bf(xe.x); e[1] = f2bf(xe.y); e[2] = f2bf(xe.z); e[3] = f2bf(xe.w);
      e[4] = (short)0x3F80;
      *(short8*)&ext2[cur ^ 1][tid * 40] = e;
    }

    // ---- L1: xp loads for this step (consumed post-MFMA) ----
    ushort4 xq[3][2];
    if (LAYER == 1) {
      const unsigned short* base = xp1g + ((size_t)t * 256 + (b0 + l15)) * 768;
      #pragma unroll
      for (int g = 0; g < 3; ++g)
        #pragma unroll
        for (int s = 0; s < 2; ++s)
          xq[g][s] = *(const ushort4*)(base + g * 256 + 32 * w + 16 * s + lhi * 4);
    }

    // ---- h0c writeback of h_{t-1} (L0) ----
    if (LAYER == 0 && t > 0) {
      const int tprev = dir ? 256 - t : t - 1;
      const int br = tid >> 5, c = tid & 31;
      short8 v = *(const short8*)&hb[cur][br * 256 + ((c ^ (br & 7)) << 3)];
      __builtin_nontemporal_store(v,
          (short8*)(h0c + ((size_t)(b0 + br) * 256 + tprev) * 512 + dir * 256 + c * 8));
    }

    // ---- B fragments from swizzled LDS ----
    short8 bfr[8];
    #pragma unroll
    for (int kk = 0; kk < 8; ++kk) {
      const int g = kk * 4 + lhi;
      bfr[kk] = *(const short8*)&hb[cur][l15 * 256 + ((g ^ (l15 & 7)) << 3)];
    }
    const int ecur = (LAYER == 0) ? cur : 0;
    short8 bext = *(const short8*)&ext2[ecur][l15 * 40 + lhi * 8];

    // ---- MFMA: 48 + 6 ext ----
    f32x4 acc[3][2] = {};
    #pragma unroll
    for (int kk = 0; kk < 8; ++kk)
      #pragma unroll
      for (int g = 0; g < 3; ++g)
        #pragma unroll
        for (int s = 0; s < 2; ++s)
          acc[g][s] = __builtin_amdgcn_mfma_f32_16x16x32_bf16(a[g][s][kk], bfr[kk], acc[g][s], 0, 0, 0);
    #pragma unroll
    for (int g = 0; g < 3; ++g)
      #pragma unroll
      for (int s = 0; s < 2; ++s)
        acc[g][s] = __builtin_amdgcn_mfma_f32_16x16x32_bf16(a[g][s][8], bext, acc[g][s], 0, 0, 0);

    // ---- x_t for the n-gate input projection (L0) ----
    float xt[4];
    if (LAYER == 0) {
      sh4 xe = *(const sh4*)&ext2[cur][l15 * 40];
      #pragma unroll
      for (int j = 0; j < 4; ++j) xt[j] = bf2f((unsigned short)xe[j]);
    }

    // ---- elementwise GRU cell + write h_t -> hb[cur^1] ----
    #pragma unroll
    for (int s = 0; s < 2; ++s) {
      float hv[4];
      #pragma unroll
      for (int i = 0; i < 4; ++i) {
        float r, z, n;
        if (LAYER == 0) {
          r = sigf(acc[0][s][i]);            // Whh_r h + Wih_r x + biases (ext)
          z = sigf(acc[1][s][i]);
          const float4 ww = wn4[s][i];
          const float xn = xt[0] * ww.x + xt[1] * ww.y + xt[2] * ww.z + xt[3] * ww.w + bihn[s][i];
          n = tanhf_(xn + r * acc[2][s][i]); // acc2 = Whh_n h + bhh_n (ext)
        } else {
          r = sigf(acc[0][s][i] + bf2f(US4_GET(xq[0][s], i)));  // xp has bih+bhh
          z = sigf(acc[1][s][i] + bf2f(US4_GET(xq[1][s], i)));
          n = tanhf_(bf2f(US4_GET(xq[2][s], i)) + r * acc[2][s][i]);
        }
        const float h = n + z * (hreg[s][i] - n);
        hreg[s][i] = h;
        hv[i] = h;
      }
      // packed b64 write: granule gsw, shorts (lhi&1)*4 .. +3
      const int gsw = 4 * w + 2 * s + (lhi >> 1);
      const int so = l15 * 256 + ((gsw ^ (l15 & 7)) << 3) + (lhi & 1) * 4;
      unsigned p01 = (unsigned)(unsigned short)f2bf(hv[0]) |
                     ((unsigned)(unsigned short)f2bf(hv[1]) << 16);
      unsigned p23 = (unsigned)(unsigned short)f2bf(hv[2]) |
                     ((unsigned)(unsigned short)f2bf(hv[3]) << 16);
      uint2 pk; pk.x = p01; pk.y = p23;
      *(uint2*)&hb[cur ^ 1][so] = pk;
    }
    __syncthreads();
  }

  // tail: h_255 writeback (sits in hb[0] after t=255)
  if (LAYER == 0) {
    const int tlast = dir ? 0 : 255;
    const int br = tid >> 5, c = tid & 31;
    short8 v = *(const short8*)&hb[0][br * 256 + ((c ^ (br & 7)) << 3)];
    __builtin_nontemporal_store(v,
        (short8*)(h0c + ((size_t)(b0 + br) * 256 + tlast) * 512 + dir * 256 + c * 8));
  } else {
    #pragma unroll
    for (int s = 0; s < 2; ++s)
      #pragma unroll
      for (int i = 0; i < 4; ++i)
        hfl[(size_t)(b0 + l15) * 256 + 32 * w + 16 * s + lhi * 4 + i] = hreg[s][i];
  }
}

// --------------------------- xp1 GEMM --------------------------------------
// [65536,512]@[512,768]^T bf16 -> xp1g[t][b][768] with bih1 (+bhh1 for r/z).
__global__ __launch_bounds__(256, 2) void xp1_gemm(
    const short* __restrict__ h0c, const short* __restrict__ w1b,
    const float* __restrict__ bih1, const float* __restrict__ bhh1,
    unsigned short* __restrict__ xp1g) {
  const int mb = blockIdx.x, nb = blockIdx.y;
  const int tid = threadIdx.x;
  const int w = tid >> 6, l = tid & 63, l15 = l & 15, lhi = l >> 4;
  const int wm = w >> 1, wn = w & 1;
  __shared__ __align__(16) short As[128 * 64];
  __shared__ __align__(16) short Bs[128 * 64];
  f32x4 acc[4][4] = {};

  for (int ks = 0; ks < 8; ++ks) {
    short8 sa[4], sb[4];
    #pragma unroll
    for (int c = 0; c < 4; ++c) {
      int li = w * 256 + c * 64 + l;
      int row = li >> 3, cgr = li & 7;
      sa[c] = *(const short8*)(h0c + (size_t)(mb * 128 + row) * 512 + ks * 64 + cgr * 8);
      sb[c] = *(const short8*)(w1b + (size_t)(nb * 128 + row) * 512 + ks * 64 + cgr * 8);
    }
    __syncthreads();
    #pragma unroll
    for (int c = 0; c < 4; ++c) {
      int li = w * 256 + c * 64 + l;
      int row = li >> 3, cgr = li & 7;
      int sl = ((cgr ^ (row & 7)) << 3);
      *(short8*)&As[row * 64 + sl] = sa[c];
      *(short8*)&Bs[row * 64 + sl] = sb[c];
    }
    __syncthreads();
    short8 af[4][2], bfr[4][2];
    #pragma unroll
    for (int mt = 0; mt < 4; ++mt)
      #pragma unroll
      for (int kk = 0; kk < 2; ++kk) {
        int row = wm * 64 + mt * 16 + l15;
        int g = kk * 4 + lhi;
        af[mt][kk] = *(const short8*)&As[row * 64 + ((g ^ (row & 7)) << 3)];
      }
    #pragma unroll
    for (int nt2 = 0; nt2 < 4; ++nt2)
      #pragma unroll
      for (int kk = 0; kk < 2; ++kk) {
        int row = wn * 64 + nt2 * 16 + l15;
        int g = kk * 4 + lhi;
        bfr[nt2][kk] = *(const short8*)&Bs[row * 64 + ((g ^ (row & 7)) << 3)];
      }
    #pragma unroll
    for (int kk = 0; kk < 2; ++kk)
      #pragma unroll
      for (int mt = 0; mt < 4; ++mt)
        #pragma unroll
        for (int nt2 = 0; nt2 < 4; ++nt2)
          acc[mt][nt2] = __builtin_amdgcn_mfma_f32_16x16x32_bf16(
              af[mt][kk], bfr[nt2][kk], acc[mt][nt2], 0, 0, 0);
  }

  #pragma unroll
  for (int nt2 = 0; nt2 < 4; ++nt2) {
    const int gate = nb * 128 + wn * 64 + nt2 * 16 + l15;
    const float bias = bih1[gate] + ((gate < 512) ? bhh1[gate] : 0.f);
    #pragma unroll
    for (int mt = 0; mt < 4; ++mt)
      #pragma unroll
      for (int i = 0; i < 4; ++i) {
        const int rt = mb * 128 + wm * 64 + mt * 16 + lhi * 4 + i;
        const int b = rt >> 8, tt = rt & 255;
        xp1g[((size_t)tt * 256 + b) * 768 + gate] =
            (unsigned short)f2bf(acc[mt][nt2][i] + bias);
      }
  }
}

// --------------------------- layer-1 bwd single step -----------------------
__global__ __launch_bounds__(256) void bwd255(
    const short* __restrict__ h0c, const float* __restrict__ wih1,
    const float* __restrict__ bih1, const float* __restrict__ bhh1,
    float* __restrict__ hb) {
  const int b = blockIdx.x, j = threadIdx.x;
  __shared__ __align__(16) float hrow[512];
  const unsigned short* hr = (const unsigned short*)(h0c + (size_t)(b * 256 + 255) * 512);
  for (int k = j; k < 512; k += 256) hrow[k] = bf2f(hr[k]);
  __syncthreads();
  const float4* hr4 = (const float4*)hrow;
  float g[3];
  #pragma unroll
  for (int gi = 0; gi < 3; ++gi) {
    const float4* wr = (const float4*)(wih1 + (size_t)768 * 512 + (size_t)(gi * 256 + j) * 512);
    float s = 0.f;
    #pragma unroll 4
    for (int k = 0; k < 128; ++k) {
      float4 aq = hr4[k], bq = wr[k];
      s += aq.x * bq.x + aq.y * bq.y + aq.z * bq.z + aq.w * bq.w;
    }
    g[gi] = s + bih1[768 + gi * 256 + j];
  }
  float r = sigf(g[0] + bhh1[768 + j]);
  float z = sigf(g[1] + bhh1[768 + 256 + j]);
  float n = tanhf_(g[2] + r * bhh1[768 + 512 + j]);
  hb[b * 256 + j] = (1.f - z) * n;
}

// --------------------------- head ------------------------------------------
__global__ __launch_bounds__(64) void head(
    const float* __restrict__ hf, const float* __restrict__ hb,
    const float* __restrict__ wout, const float* __restrict__ bout,
    float* __restrict__ out) {
  const int b = blockIdx.x, l = threadIdx.x;
  float s0 = 0.f, s1 = 0.f, s2 = 0.f;
  for (int k = l; k < 256; k += 64) {
    float v = hf[b * 256 + k] + hb[b * 256 + k];
    s0 += v * wout[k];
    s1 += v * wout[256 + k];
    s2 += v * wout[512 + k];
  }
  #pragma unroll
  for (int off = 32; off > 0; off >>= 1) {
    s0 += __shfl_down(s0, off);
    s1 += __shfl_down(s1, off);
    s2 += __shfl_down(s2, off);
  }
  if (l == 0) {
    s0 += bout[0]; s1 += bout[1]; s2 += bout[2];
    float m = fmaxf(s0, fmaxf(s1, s2));
    float e0 = __expf(s0 - m), e1 = __expf(s1 - m), e2 = __expf(s2 - m);
    float inv = 1.f / (e0 + e1 + e2);
    out[b * 3 + 0] = e0 * inv;
    out[b * 3 + 1] = e1 * inv;
    out[b * 3 + 2] = e2 * inv;
  }
}

// --------------------------- launch ----------------------------------------
extern "C" void kernel_launch(void* const* d_in, const int* in_sizes, int n_in,
                              void* d_out, int out_size, void* d_ws, size_t ws_size,
                              hipStream_t stream) {
  const float* x    = (const float*)d_in[0];
  const float* wih0 = (const float*)d_in[1];
  const float* whh0 = (const float*)d_in[2];
  const float* bih0 = (const float*)d_in[3];
  const float* bhh0 = (const float*)d_in[4];
  const float* wih1 = (const float*)d_in[5];
  const float* whh1 = (const float*)d_in[6];
  const float* bih1 = (const float*)d_in[7];
  const float* bhh1 = (const float*)d_in[8];
  const float* wout = (const float*)d_in[9];
  const float* bout = (const float*)d_in[10];
  float* out = (float*)d_out;

  char* ws = (char*)d_ws;
  short* wfall          = (short*)(ws + 0);
  short* w1b            = (short*)(ws + 1327104);
  short* h0c            = (short*)(ws + 2113536);
  unsigned short* xp1g  = (unsigned short*)(ws + 69222400);
  float* hb255          = (float*)(ws + 169885696);
  float* hfl            = (float*)(ws + 170147840);

  prep_wf<<<324, 256, 0, stream>>>(whh0, whh1, wih0, bih0, bhh0, bhh1, wfall);
  prep_w1b<<<192, 256, 0, stream>>>(wih1, w1b);
  gru_step<0><<<32, 512, 0, stream>>>(x, wih0, bih0, wfall, nullptr, h0c, nullptr);
  bwd255<<<256, 256, 0, stream>>>(h0c, wih1, bih1, bhh1, hb255);
  xp1_gemm<<<dim3(512, 6), 256, 0, stream>>>(h0c, w1b, bih1, bhh1, xp1g);
  gru_step<1><<<16, 512, 0, stream>>>(nullptr, nullptr, nullptr, wfall, xp1g, nullptr, hfl);
  head<<<256, 64, 0, stream>>>(hfl, hb255, wout, bout, out);
}

// Round 4
// 1330.129 us; speedup vs baseline: 2.4500x; 1.8145x over previous
//
#include <hip/hip_runtime.h>

// ---------------------------------------------------------------------------
// Bidirectional 2-layer GRU (B=256, T=256, H=256, IN0=4) + head.  v4.
//
// v1: weights streamed from L2 -> per-CU L2-port bound (~12k cyc/step).
// v2: cross-WG h exchange via global -> XCD-coherence disaster.
// v3: "weights in regs" DIDN'T HAPPEN: 8-wave WG caps at 256 VGPR/wave,
//     demand was ~300 -> compiler allocated 128 and re-streamed weights
//     from L2 every step (VGPR_Count=128 proved it). Same time as v1.
// v4: make it fit. Per wave: 6 of 8 K-slices of Whh in regs (144 VGPR),
//     2 K-slices in LDS (96 KB, read back per step at 256 B/cy);
//     input-proj + all biases via a 4-group ext MFMA column (32 VGPR)
//     instead of 40 VGPRs of VALU coefficients. Demand ~250 <= 256.
//
// Workspace (bytes):
//   0          whhf  : 3*48*8*64*16  = 1,179,648   Whh frag-packed
//   1179648    wextf : 3*4*16*64*16  =   196,608   ext frag-packed
//   1376256    w1b   : 768*512*2     =   786,432
//   2162688    h0c   : 65536*512*2   = 67,108,864  rows b*256+t, 512 cols
//   69271552   xp1g  : [t][b][768]*2 = 100,663,296
//   169934848  hb255 : 256*256*4     =   262,144
//   170196992  hfl   : 256*256*4     =   262,144
// ---------------------------------------------------------------------------

typedef __attribute__((ext_vector_type(8))) short short8;
typedef __attribute__((ext_vector_type(4))) short sh4;
typedef __attribute__((ext_vector_type(4))) float f32x4;

__device__ __forceinline__ short f2bf(float f) {
  union { float f; unsigned u; } v; v.f = f;
  unsigned r = v.u + 0x7fffu + ((v.u >> 16) & 1u);
  return (short)(r >> 16);
}
__device__ __forceinline__ float bf2f(unsigned short b) {
  union { unsigned u; float f; } v; v.u = ((unsigned)b) << 16; return v.f;
}
__device__ __forceinline__ float sigf(float x) {
  return __builtin_amdgcn_rcpf(1.f + __expf(-x));
}
__device__ __forceinline__ float tanhf_(float x) {
  return 1.f - 2.f * __builtin_amdgcn_rcpf(1.f + __expf(2.f * x));
}
__device__ __forceinline__ void gload_lds16(const void* g, void* s) {
  __builtin_amdgcn_global_load_lds(
      (const __attribute__((address_space(1))) unsigned int*)g,
      (__attribute__((address_space(3))) unsigned int*)s, 16, 0, 0);
}
#define US4_GET(v, i) ((i) == 0 ? (v).x : (i) == 1 ? (v).y : (i) == 2 ? (v).z : (v).w)

// --------------------------- prep kernels ----------------------------------
// whhf[mat][nt48][kk8][lane][8] : W[mat](row=nt*16+l15, k=kk*32+lhi*8+s)
//   mats {Whh0d0, Whh0d1, Whh1d0}
// wextf[mat][grp4][tt16][lane][8] : ext column frags, c = lhi*8+s
//   grp0 r : c<4 -> Wih0_r[row][c] ; c==4 -> bih0+bhh0   (m<2 only)
//   grp1 z : likewise for z rows                          (m<2 only)
//   grp2 nh: c==4 -> bhh_n (m<2: bhh0 ; m==2: bhh1)
//   grp3 nx: c<4 -> Wih0_n[row][c] ; c==4 -> bih0_n       (m<2 only)
__global__ __launch_bounds__(256) void prep_wf(
    const float* __restrict__ whh0, const float* __restrict__ whh1,
    const float* __restrict__ wih0, const float* __restrict__ bih0,
    const float* __restrict__ bhh0, const float* __restrict__ bhh1,
    short* __restrict__ whhf, short* __restrict__ wextf) {
  int tid = blockIdx.x * 256 + threadIdx.x;     // 0..86015
  if (tid < 73728) {
    int l = tid & 63;
    int rest = tid >> 6;
    int kk = rest & 7;
    int rest2 = rest >> 3;
    int nt = rest2 % 48;
    int m  = rest2 / 48;
    int row = nt * 16 + (l & 15);
    int k0  = kk * 32 + (l >> 4) * 8;
    const float* src = (m < 2) ? (whh0 + (size_t)m * 768 * 256) : whh1;
    const float* p = src + (size_t)row * 256 + k0;
    short8 o;
    #pragma unroll
    for (int s = 0; s < 8; ++s) o[s] = f2bf(p[s]);
    ((short8*)whhf)[tid] = o;
  } else {
    int j = tid - 73728;                        // 0..12287
    int l = j & 63;
    int tt = (j >> 6) & 15;
    int grp = (j >> 10) & 3;
    int m = j >> 12;
    int l15 = l & 15, lhi = l >> 4;
    int gate = (grp <= 1) ? grp : 2;
    int row = gate * 256 + tt * 16 + l15;
    short8 o = {};
    #pragma unroll
    for (int s = 0; s < 8; ++s) {
      int c = lhi * 8 + s;
      float v = 0.f;
      if (grp == 2) {
        if (c == 4) v = (m < 2) ? bhh0[m * 768 + row] : bhh1[row];
      } else if (m < 2) {
        if (c < 4) v = wih0[((size_t)m * 768 + row) * 4 + c];
        else if (c == 4) {
          v = bih0[m * 768 + row];
          if (grp < 2) v += bhh0[m * 768 + row];
        }
      }
      o[s] = f2bf(v);
    }
    ((short8*)wextf)[j] = o;
  }
}

__global__ __launch_bounds__(256) void prep_w1b(const float* __restrict__ wih1,
                                                short* __restrict__ out) {
  int i = blockIdx.x * 256 + threadIdx.x;
  const float* p = wih1 + (size_t)i * 8;
  short8 o;
  #pragma unroll
  for (int s = 0; s < 8; ++s) o[s] = f2bf(p[s]);
  ((short8*)out)[i] = o;
}

// --------------------------- recurrence ------------------------------------
// 8 waves; wave w owns hidden cols [32w,32w+32): tiles g*16+2w+{0,1}.
// Whh kk 0..5 in regs (36 frags), kk 6..7 in LDS (96 KB).
// h panel [16][256] bf16 double-buffered, 16B-granule XOR swizzle.
template <int LAYER>
__global__ __launch_bounds__(512, 2) void gru_step(
    const float* __restrict__ x,        // L0 [256][256][4]
    const short* __restrict__ wf,       // whhf (wextf at +589824 shorts)
    const unsigned short* __restrict__ xp1g, // L1 [t][b][768]
    short* __restrict__ h0c,            // L0 out: rows b*256+t, 512 cols
    float* __restrict__ hfl) {          // L1 out [b][256]
  const int wg  = blockIdx.x;
  const int dir = (LAYER == 0) ? (wg >> 4) : 0;
  const int bt  = (LAYER == 0) ? (wg & 15) : wg;
  const int b0  = bt * 16;
  const int tid = threadIdx.x;
  const int w = tid >> 6, l = tid & 63, l15 = l & 15, lhi = l >> 4;
  const int mat = (LAYER == 0) ? dir : 2;
  const short* wext = wf + 589824;

  __shared__ __align__(16) short wlds[49152];   // 96 KB: [w][t6][kkl][lane*8]
  __shared__ __align__(16) short hb[2][4096];   // 16 KB
  __shared__ __align__(16) short ext2[2][640];  // 2.5 KB (L0 only)

  // ---- stage kk 6..7 weight frags into LDS (wave-linear dest) ----
  #pragma unroll
  for (int t6 = 0; t6 < 6; ++t6) {
    const int g = t6 >> 1, s = t6 & 1;
    const int tile = g * 16 + 2 * w + s;
    #pragma unroll
    for (int kkl = 0; kkl < 2; ++kkl)
      gload_lds16(wf + (((size_t)(mat * 48 + tile) * 8) + 6 + kkl) * 512 + l * 8,
                  &wlds[((w * 6 + t6) * 2 + kkl) * 512]);
  }

  for (int i = tid; i < 4096; i += 512) hb[0][i] = 0;
  for (int i = tid; i < 1280; i += 512) ((short*)ext2)[i] = 0;

  // ---- persistent regs: Whh kk<6 + ext frags ----
  short8 wreg[3][2][6];
  #pragma unroll
  for (int g = 0; g < 3; ++g)
    #pragma unroll
    for (int s = 0; s < 2; ++s) {
      const int tile = g * 16 + 2 * w + s;
      #pragma unroll
      for (int kk = 0; kk < 6; ++kk)
        wreg[g][s][kk] = ((const short8*)wf)[((size_t)(mat * 48 + tile) * 8 + kk) * 64 + l];
    }
  short8 aext[4][2];
  #pragma unroll
  for (int grp = 0; grp < 4; ++grp) {
    if (LAYER == 1 && grp != 2) continue;
    #pragma unroll
    for (int s = 0; s < 2; ++s)
      aext[grp][s] = ((const short8*)wext)[((size_t)(mat * 4 + grp) * 16 + 2 * w + s) * 64 + l];
  }

  __syncthreads();
  if (LAYER == 0 && tid < 16) {
    const int t0 = dir ? 255 : 0;
    float4 xe = ((const float4*)x)[(size_t)(b0 + tid) * 256 + t0];
    short8 e = {};
    e[0] = f2bf(xe.x); e[1] = f2bf(xe.y); e[2] = f2bf(xe.z); e[3] = f2bf(xe.w);
    e[4] = (short)0x3F80;
    *(short8*)&ext2[0][tid * 40] = e;
  }
  float hreg[2][4] = {{0, 0, 0, 0}, {0, 0, 0, 0}};
  __syncthreads();

  for (int t = 0; t < 256; ++t) {
    const int cur = t & 1;

    // ---- prefetch x_{t+1} -> ext2[cur^1] (L0) ----
    if (LAYER == 0 && tid < 16 && t < 255) {
      const int tn = dir ? 254 - t : t + 1;
      float4 xe = ((const float4*)x)[(size_t)(b0 + tid) * 256 + tn];
      short8 e = {};
      e[0] = f2bf(xe.x); e[1] = f2bf(xe.y); e[2] = f2bf(xe.z); e[3] = f2bf(xe.w);
      e[4] = (short)0x3F80;
      *(short8*)&ext2[cur ^ 1][tid * 40] = e;
    }

    // ---- L1: xp loads for this step ----
    ushort4 xq[3][2];
    if (LAYER == 1) {
      const unsigned short* base = xp1g + ((size_t)t * 256 + (b0 + l15)) * 768;
      #pragma unroll
      for (int g = 0; g < 3; ++g)
        #pragma unroll
        for (int s = 0; s < 2; ++s)
          xq[g][s] = *(const ushort4*)(base + g * 256 + 32 * w + 16 * s + lhi * 4);
    }

    // ---- h0c writeback of h_{t-1} (L0) ----
    if (LAYER == 0 && t > 0) {
      const int tprev = dir ? 256 - t : t - 1;
      const int br = tid >> 5, c = tid & 31;
      short8 v = *(const short8*)&hb[cur][br * 256 + ((c ^ (br & 7)) << 3)];
      __builtin_nontemporal_store(v,
          (short8*)(h0c + ((size_t)(b0 + br) * 256 + tprev) * 512 + dir * 256 + c * 8));
    }

    // ---- gates GEMM: kk-outer, weights from regs (kk<6) or LDS (kk>=6) ----
    f32x4 acc[3][2] = {};
    f32x4 accx[2] = {};
    #pragma unroll
    for (int kk = 0; kk < 8; ++kk) {
      const int gidx = kk * 4 + lhi;
      const short8 bfr = *(const short8*)&hb[cur][l15 * 256 + ((gidx ^ (l15 & 7)) << 3)];
      if (kk < 6) {
        #pragma unroll
        for (int g = 0; g < 3; ++g)
          #pragma unroll
          for (int s = 0; s < 2; ++s)
            acc[g][s] = __builtin_amdgcn_mfma_f32_16x16x32_bf16(wreg[g][s][kk], bfr, acc[g][s], 0, 0, 0);
      } else {
        #pragma unroll
        for (int g = 0; g < 3; ++g)
          #pragma unroll
          for (int s = 0; s < 2; ++s) {
            const short8 wl =
                *(const short8*)&wlds[((w * 6 + g * 2 + s) * 2 + (kk - 6)) * 512 + l * 8];
            acc[g][s] = __builtin_amdgcn_mfma_f32_16x16x32_bf16(wl, bfr, acc[g][s], 0, 0, 0);
          }
      }
    }
    // ---- ext column (input proj + biases) ----
    short8 bext;
    if (LAYER == 0) {
      bext = *(const short8*)&ext2[cur][l15 * 40 + lhi * 8];
    } else {
      short8 e = {};
      if (lhi == 0) e[4] = (short)0x3F80;
      bext = e;
    }
    if (LAYER == 0) {
      #pragma unroll
      for (int s = 0; s < 2; ++s) {
        acc[0][s] = __builtin_amdgcn_mfma_f32_16x16x32_bf16(aext[0][s], bext, acc[0][s], 0, 0, 0);
        acc[1][s] = __builtin_amdgcn_mfma_f32_16x16x32_bf16(aext[1][s], bext, acc[1][s], 0, 0, 0);
        acc[2][s] = __builtin_amdgcn_mfma_f32_16x16x32_bf16(aext[2][s], bext, acc[2][s], 0, 0, 0);
        accx[s]   = __builtin_amdgcn_mfma_f32_16x16x32_bf16(aext[3][s], bext, accx[s], 0, 0, 0);
      }
    } else {
      #pragma unroll
      for (int s = 0; s < 2; ++s)
        acc[2][s] = __builtin_amdgcn_mfma_f32_16x16x32_bf16(aext[2][s], bext, acc[2][s], 0, 0, 0);
    }

    // ---- elementwise GRU cell + write h_t -> hb[cur^1] ----
    #pragma unroll
    for (int s = 0; s < 2; ++s) {
      float hv[4];
      #pragma unroll
      for (int i = 0; i < 4; ++i) {
        float r, z, n;
        if (LAYER == 0) {
          r = sigf(acc[0][s][i]);            // Whh_r h + Wih_r x + br (ext)
          z = sigf(acc[1][s][i]);
          n = tanhf_(accx[s][i] + r * acc[2][s][i]);  // nx + r*(Whh_n h + bhh_n)
        } else {
          r = sigf(acc[0][s][i] + bf2f(US4_GET(xq[0][s], i)));
          z = sigf(acc[1][s][i] + bf2f(US4_GET(xq[1][s], i)));
          n = tanhf_(bf2f(US4_GET(xq[2][s], i)) + r * acc[2][s][i]);
        }
        const float h = n + z * (hreg[s][i] - n);
        hreg[s][i] = h;
        hv[i] = h;
      }
      const int gsw = 4 * w + 2 * s + (lhi >> 1);
      const int so = l15 * 256 + ((gsw ^ (l15 & 7)) << 3) + (lhi & 1) * 4;
      unsigned p01 = (unsigned)(unsigned short)f2bf(hv[0]) |
                     ((unsigned)(unsigned short)f2bf(hv[1]) << 16);
      unsigned p23 = (unsigned)(unsigned short)f2bf(hv[2]) |
                     ((unsigned)(unsigned short)f2bf(hv[3]) << 16);
      uint2 pk; pk.x = p01; pk.y = p23;
      *(uint2*)&hb[cur ^ 1][so] = pk;
    }
    __syncthreads();
  }

  // tail: h_255 writeback (in hb[0] after the loop)
  if (LAYER == 0) {
    const int tlast = dir ? 0 : 255;
    const int br = tid >> 5, c = tid & 31;
    short8 v = *(const short8*)&hb[0][br * 256 + ((c ^ (br & 7)) << 3)];
    __builtin_nontemporal_store(v,
        (short8*)(h0c + ((size_t)(b0 + br) * 256 + tlast) * 512 + dir * 256 + c * 8));
  } else {
    #pragma unroll
    for (int s = 0; s < 2; ++s)
      #pragma unroll
      for (int i = 0; i < 4; ++i)
        hfl[(size_t)(b0 + l15) * 256 + 32 * w + 16 * s + lhi * 4 + i] = hreg[s][i];
  }
}

// --------------------------- xp1 GEMM --------------------------------------
// [65536,512]@[512,768]^T bf16 -> xp1g[t][b][768] with bih1 (+bhh1 for r/z).
__global__ __launch_bounds__(256, 2) void xp1_gemm(
    const short* __restrict__ h0c, const short* __restrict__ w1b,
    const float* __restrict__ bih1, const float* __restrict__ bhh1,
    unsigned short* __restrict__ xp1g) {
  const int mb = blockIdx.x, nb = blockIdx.y;
  const int tid = threadIdx.x;
  const int w = tid >> 6, l = tid & 63, l15 = l & 15, lhi = l >> 4;
  const int wm = w >> 1, wn = w & 1;
  __shared__ __align__(16) short As[128 * 64];
  __shared__ __align__(16) short Bs[128 * 64];
  f32x4 acc[4][4] = {};

  for (int ks = 0; ks < 8; ++ks) {
    short8 sa[4], sb[4];
    #pragma unroll
    for (int c = 0; c < 4; ++c) {
      int li = w * 256 + c * 64 + l;
      int row = li >> 3, cgr = li & 7;
      sa[c] = *(const short8*)(h0c + (size_t)(mb * 128 + row) * 512 + ks * 64 + cgr * 8);
      sb[c] = *(const short8*)(w1b + (size_t)(nb * 128 + row) * 512 + ks * 64 + cgr * 8);
    }
    __syncthreads();
    #pragma unroll
    for (int c = 0; c < 4; ++c) {
      int li = w * 256 + c * 64 + l;
      int row = li >> 3, cgr = li & 7;
      int sl = ((cgr ^ (row & 7)) << 3);
      *(short8*)&As[row * 64 + sl] = sa[c];
      *(short8*)&Bs[row * 64 + sl] = sb[c];
    }
    __syncthreads();
    short8 af[4][2], bfr[4][2];
    #pragma unroll
    for (int mt = 0; mt < 4; ++mt)
      #pragma unroll
      for (int kk = 0; kk < 2; ++kk) {
        int row = wm * 64 + mt * 16 + l15;
        int g = kk * 4 + lhi;
        af[mt][kk] = *(const short8*)&As[row * 64 + ((g ^ (row & 7)) << 3)];
      }
    #pragma unroll
    for (int nt2 = 0; nt2 < 4; ++nt2)
      #pragma unroll
      for (int kk = 0; kk < 2; ++kk) {
        int row = wn * 64 + nt2 * 16 + l15;
        int g = kk * 4 + lhi;
        bfr[nt2][kk] = *(const short8*)&Bs[row * 64 + ((g ^ (row & 7)) << 3)];
      }
    #pragma unroll
    for (int kk = 0; kk < 2; ++kk)
      #pragma unroll
      for (int mt = 0; mt < 4; ++mt)
        #pragma unroll
        for (int nt2 = 0; nt2 < 4; ++nt2)
          acc[mt][nt2] = __builtin_amdgcn_mfma_f32_16x16x32_bf16(
              af[mt][kk], bfr[nt2][kk], acc[mt][nt2], 0, 0, 0);
  }

  #pragma unroll
  for (int nt2 = 0; nt2 < 4; ++nt2) {
    const int gate = nb * 128 + wn * 64 + nt2 * 16 + l15;
    const float bias = bih1[gate] + ((gate < 512) ? bhh1[gate] : 0.f);
    #pragma unroll
    for (int mt = 0; mt < 4; ++mt)
      #pragma unroll
      for (int i = 0; i < 4; ++i) {
        const int rt = mb * 128 + wm * 64 + mt * 16 + lhi * 4 + i;
        const int b = rt >> 8, tt = rt & 255;
        xp1g[((size_t)tt * 256 + b) * 768 + gate] =
            (unsigned short)f2bf(acc[mt][nt2][i] + bias);
      }
  }
}

// --------------------------- layer-1 bwd single step -----------------------
__global__ __launch_bounds__(256) void bwd255(
    const short* __restrict__ h0c, const float* __restrict__ wih1,
    const float* __restrict__ bih1, const float* __restrict__ bhh1,
    float* __restrict__ hb) {
  const int b = blockIdx.x, j = threadIdx.x;
  __shared__ __align__(16) float hrow[512];
  const unsigned short* hr = (const unsigned short*)(h0c + (size_t)(b * 256 + 255) * 512);
  for (int k = j; k < 512; k += 256) hrow[k] = bf2f(hr[k]);
  __syncthreads();
  const float4* hr4 = (const float4*)hrow;
  float g[3];
  #pragma unroll
  for (int gi = 0; gi < 3; ++gi) {
    const float4* wr = (const float4*)(wih1 + (size_t)768 * 512 + (size_t)(gi * 256 + j) * 512);
    float s = 0.f;
    #pragma unroll 4
    for (int k = 0; k < 128; ++k) {
      float4 aq = hr4[k], bq = wr[k];
      s += aq.x * bq.x + aq.y * bq.y + aq.z * bq.z + aq.w * bq.w;
    }
    g[gi] = s + bih1[768 + gi * 256 + j];
  }
  float r = sigf(g[0] + bhh1[768 + j]);
  float z = sigf(g[1] + bhh1[768 + 256 + j]);
  float n = tanhf_(g[2] + r * bhh1[768 + 512 + j]);
  hb[b * 256 + j] = (1.f - z) * n;
}

// --------------------------- head ------------------------------------------
__global__ __launch_bounds__(64) void head(
    const float* __restrict__ hf, const float* __restrict__ hb,
    const float* __restrict__ wout, const float* __restrict__ bout,
    float* __restrict__ out) {
  const int b = blockIdx.x, l = threadIdx.x;
  float s0 = 0.f, s1 = 0.f, s2 = 0.f;
  for (int k = l; k < 256; k += 64) {
    float v = hf[b * 256 + k] + hb[b * 256 + k];
    s0 += v * wout[k];
    s1 += v * wout[256 + k];
    s2 += v * wout[512 + k];
  }
  #pragma unroll
  for (int off = 32; off > 0; off >>= 1) {
    s0 += __shfl_down(s0, off);
    s1 += __shfl_down(s1, off);
    s2 += __shfl_down(s2, off);
  }
  if (l == 0) {
    s0 += bout[0]; s1 += bout[1]; s2 += bout[2];
    float m = fmaxf(s0, fmaxf(s1, s2));
    float e0 = __expf(s0 - m), e1 = __expf(s1 - m), e2 = __expf(s2 - m);
    float inv = 1.f / (e0 + e1 + e2);
    out[b * 3 + 0] = e0 * inv;
    out[b * 3 + 1] = e1 * inv;
    out[b * 3 + 2] = e2 * inv;
  }
}

// --------------------------- launch ----------------------------------------
extern "C" void kernel_launch(void* const* d_in, const int* in_sizes, int n_in,
                              void* d_out, int out_size, void* d_ws, size_t ws_size,
                              hipStream_t stream) {
  const float* x    = (const float*)d_in[0];
  const float* wih0 = (const float*)d_in[1];
  const float* whh0 = (const float*)d_in[2];
  const float* bih0 = (const float*)d_in[3];
  const float* bhh0 = (const float*)d_in[4];
  const float* wih1 = (const float*)d_in[5];
  const float* whh1 = (const float*)d_in[6];
  const float* bih1 = (const float*)d_in[7];
  const float* bhh1 = (const float*)d_in[8];
  const float* wout = (const float*)d_in[9];
  const float* bout = (const float*)d_in[10];
  float* out = (float*)d_out;

  char* ws = (char*)d_ws;
  short* whhf           = (short*)(ws + 0);
  short* wextf          = (short*)(ws + 1179648);
  short* w1b            = (short*)(ws + 1376256);
  short* h0c            = (short*)(ws + 2162688);
  unsigned short* xp1g  = (unsigned short*)(ws + 69271552);
  float* hb255          = (float*)(ws + 169934848);
  float* hfl            = (float*)(ws + 170196992);

  prep_wf<<<336, 256, 0, stream>>>(whh0, whh1, wih0, bih0, bhh0, bhh1, whhf, wextf);
  prep_w1b<<<192, 256, 0, stream>>>(wih1, w1b);
  gru_step<0><<<32, 512, 0, stream>>>(x, whhf, nullptr, h0c, nullptr);
  bwd255<<<256, 256, 0, stream>>>(h0c, wih1, bih1, bhh1, hb255);
  xp1_gemm<<<dim3(512, 6), 256, 0, stream>>>(h0c, w1b, bih1, bhh1, xp1g);
  gru_step<1><<<16, 512, 0, stream>>>(nullptr, whhf, xp1g, nullptr, hfl);
  head<<<256, 64, 0, stream>>>(hfl, hb255, wout, bout, out);
}